// Round 6
// baseline (258.148 us; speedup 1.0000x reference)
//
#include <hip/hip_runtime.h>
#include <hip/hip_bf16.h>

typedef __attribute__((ext_vector_type(8))) short short8;
typedef __attribute__((ext_vector_type(4))) float floatx4;
typedef __hip_bfloat16 bf16;

#define DIM 768
#define NH 12
#define HD 64
#define BB 16
#define NN 640
#define BH (BB*NH)          // 192
#define MROWS (BB*NN)       // 10240
#define QKVN (3*DIM)        // 2304
#define QSCALE 0.18033688011113205f   // 0.125 * log2(e)
#define LN2SQ 0.4804530139182014f     // ln(2)^2

__device__ __forceinline__ floatx4 mfma16(short8 a, short8 b, floatx4 c) {
    return __builtin_amdgcn_mfma_f32_16x16x32_bf16(a, b, c, 0, 0, 0);
}

// async global->LDS, 16B per lane; lds dest = wave-uniform base + lane*16
__device__ __forceinline__ void async_ld16(const bf16* g, bf16* l) {
    __builtin_amdgcn_global_load_lds(
        (const __attribute__((address_space(1))) void*)g,
        (__attribute__((address_space(3))) void*)l, 16, 0, 0);
}

// truncate two f32 to bf16 and pack: lo16 = a, hi16 = b  (one v_perm_b32)
__device__ __forceinline__ unsigned pack_trunc(float a, float b) {
    return __builtin_amdgcn_perm(__float_as_uint(b), __float_as_uint(a), 0x07060302u);
}

__device__ __forceinline__ float fexp2(float x) {
#if __has_builtin(__builtin_amdgcn_exp2f)
    return __builtin_amdgcn_exp2f(x);
#else
    return exp2f(x);
#endif
}

// ---------------- prep kernels ----------------

__global__ void cvt_x(const float* __restrict__ x, bf16* __restrict__ xb, int n4) {
    int i = blockIdx.x * blockDim.x + threadIdx.x;
    if (i >= n4) return;
    float4 v = ((const float4*)x)[i];
    bf16* p = xb + (size_t)i * 4;
    p[0] = __float2bfloat16(v.x);
    p[1] = __float2bfloat16(v.y);
    p[2] = __float2bfloat16(v.z);
    p[3] = __float2bfloat16(v.w);
}

// src [R][C] fp32 -> dst [C][R] bf16 ; grid (C/32, R/32), block (32,8)
__global__ void tr_cvt(const float* __restrict__ src, bf16* __restrict__ dst, int R, int C) {
    __shared__ float tile[32][33];
    int bx = blockIdx.x, by = blockIdx.y;
    int tx = threadIdx.x, ty = threadIdx.y;
    for (int j = 0; j < 4; ++j)
        tile[ty + j*8][tx] = src[(size_t)(by*32 + ty + j*8) * C + bx*32 + tx];
    __syncthreads();
    for (int j = 0; j < 4; ++j)
        dst[(size_t)(bx*32 + ty + j*8) * R + by*32 + tx] = __float2bfloat16(tile[tx][ty + j*8]);
}

// ---------------- GEMM: C = A @ B^T  (A [M][K] bf16, B [N][K] bf16) ----------------
// BK=64: 12 barriers for K=768, 32 MFMA/barrier. LDS chunk slots XOR-swizzled
// (slot = chunk ^ (row&7)) so fragment ds_read_b128s spread over all banks.
// grid (N/128, M/128), n fastest (A-panel sharing / B in XCD L2).
// MODE 0 (qkv): bf16 out + bias, QSCALE on q cols; V cols (n0>=1536) are written
//   DIRECTLY to vT[bh][d][tok] via per-wave LDS transpose (v_tr fused away).
// MODE 1 (proj): fp32 out + bias.
template<int MODE>
__global__ __launch_bounds__(256) void gemm_bt(
    const bf16* __restrict__ A, const bf16* __restrict__ B, const float* __restrict__ bias,
    int M, int N, int K,
    bf16* __restrict__ outb, bf16* __restrict__ vTo, float* __restrict__ outf)
{
    __shared__ __align__(16) bf16 As[128*64];
    __shared__ __align__(16) bf16 Bs[128*64];

    const int t = threadIdx.x;
    const int lane = t & 63, wave = t >> 6;
    const int l15 = lane & 15, quad = lane >> 4;
    const int wm = (wave >> 1) * 64, wn = (wave & 1) * 64;
    const int m0 = blockIdx.y * 128, n0 = blockIdx.x * 128;

    floatx4 acc[4][4];
    floatx4 zero = {0.f, 0.f, 0.f, 0.f};
    for (int i = 0; i < 4; ++i)
        for (int j = 0; j < 4; ++j)
            acc[i][j] = zero;

    const int sw = l15 & 7;
    for (int kk = 0; kk < K; kk += 64) {
        __syncthreads();
        for (int s = 0; s < 4; ++s) {
            int cid = s * 256 + t;
            int row = cid >> 3;
            int gc  = ((t & 7) ^ (row & 7)) << 3;   // swizzled source chunk
            int lbase = (s * 256 + wave * 64) * 8;  // wave-uniform LDS base
            async_ld16(A + (size_t)(m0 + row) * K + kk + gc, As + lbase);
            async_ld16(B + (size_t)(n0 + row) * K + kk + gc, Bs + lbase);
        }
        __syncthreads();
        short8 af0[4], af1[4], bf0[4], bf1[4];
        for (int fm = 0; fm < 4; ++fm) {
            int base = (wm + fm*16 + l15) * 64 + ((quad ^ sw) << 3);
            af0[fm] = *(const short8*)(As + base);
            af1[fm] = *(const short8*)(As + (base ^ 32));
        }
        for (int fn = 0; fn < 4; ++fn) {
            int base = (wn + fn*16 + l15) * 64 + ((quad ^ sw) << 3);
            bf0[fn] = *(const short8*)(Bs + base);
            bf1[fn] = *(const short8*)(Bs + (base ^ 32));
        }
        for (int fm = 0; fm < 4; ++fm)
            for (int fn = 0; fn < 4; ++fn) {
                acc[fm][fn] = mfma16(af0[fm], bf0[fn], acc[fm][fn]);
                acc[fm][fn] = mfma16(af1[fm], bf1[fn], acc[fm][fn]);
            }
    }

    if (MODE == 0 && n0 >= 2*DIM) {
        // ---- V block: write vT[bh][d][tok] via per-wave LDS transpose ----
        __syncthreads();                       // done reading As -> reuse as scratch
        bf16* T4 = As + wave * 2048;           // [fm][d 16][m 32-stride]
        const int bh   = (m0 / NN) * NH + ((n0 + wn) >> 6) - 24;
        const int tokb = (m0 % NN) + wm;
        for (int fn = 0; fn < 4; ++fn) {
            int n = n0 + wn + fn*16 + l15;
            float bn = bias[n];
            for (int fm = 0; fm < 4; ++fm) {
                float v0 = acc[fm][fn][0] + bn, v1 = acc[fm][fn][1] + bn;
                float v2 = acc[fm][fn][2] + bn, v3 = acc[fm][fn][3] + bn;
                *(uint2*)(T4 + fm*512 + l15*32 + quad*4) =
                    make_uint2(pack_trunc(v0, v1), pack_trunc(v2, v3));
            }
            // lane (d=l15, seg=quad) reads T4[quad][l15][0..15], writes 32 B run
            uint4 r0 = *(const uint4*)(T4 + quad*512 + l15*32);
            uint4 r1 = *(const uint4*)(T4 + quad*512 + l15*32 + 8);
            int d = fn*16 + l15;
            bf16* dst = vTo + ((size_t)bh * HD + d) * NN + tokb + quad*16;
            *(uint4*)dst = r0;
            *(uint4*)(dst + 8) = r1;
        }
        return;
    }

    for (int fm = 0; fm < 4; ++fm) {
        for (int fn = 0; fn < 4; ++fn) {
            int n = n0 + wn + fn*16 + l15;
            float bn = bias[n];
            for (int r = 0; r < 4; ++r) {
                int m = m0 + wm + fm*16 + quad*4 + r;
                float v = acc[fm][fn][r] + bn;
                if (MODE == 0) {
                    if (n < DIM) v *= QSCALE;   // pre-scale q (incl. log2e for exp2)
                    outb[(size_t)m * N + n] = __float2bfloat16(v);
                } else {
                    outf[(size_t)m * N + n] = v;
                }
            }
        }
    }
}

// ---------------- fused attention v5: barrier-free ----------------
// grid (192 bh, 5 qtile): bh fastest -> a head's q-tiles share an XCD L2.
// block 256 (4 waves); wave owns 32 q rows (two 16-row groups A/B).
// K/V fragments loaded DIRECTLY from global (L2-resident) -> no __syncthreads
// in the loop, compiler pipelines loads with fine-grained vmcnt.
// S^T formulation; log2e folded into q; P packed by truncation (v_perm).
__global__ __launch_bounds__(256) void attn_kernel(
    const bf16* __restrict__ qkv, const bf16* __restrict__ vT,
    const float* __restrict__ w2, bf16* __restrict__ ao)
{
    const int bh = blockIdx.x;
    const int b = bh / NH, h = bh - b * NH;
    const int t = threadIdx.x;
    const int wave = t >> 6, lane = t & 63;
    const int l15 = lane & 15, quad = lane >> 4;
    const int qrow0 = blockIdx.y * 128 + wave * 32;

    float w0 = w2[0], w1 = w2[1];
    float wmx = fmaxf(w0, w1);
    float e0 = __expf(w0 - wmx), e1 = __expf(w1 - wmx);
    float ws0 = e0 / (e0 + e1);
    float ws1 = (1.0f - ws0) * LN2SQ;

    // per-wave P buffers: SA | RA | SB | RB, each [16 q][40]
    __shared__ __align__(16) bf16 Pbuf[4][4*640];

    const bf16* kb = qkv + (size_t)(b*NN)*QKVN + DIM + h*HD;
    const bf16* vb = vT + (size_t)bh * HD * NN;

    const bf16* qA = qkv + (size_t)(b*NN + qrow0 + l15) * QKVN + h*HD;
    const bf16* qB = qA + (size_t)16 * QKVN;
    short8 aqA0 = *(const short8*)(qA + quad*8);
    short8 aqA1 = *(const short8*)(qA + 32 + quad*8);
    short8 aqB0 = *(const short8*)(qB + quad*8);
    short8 aqB1 = *(const short8*)(qB + 32 + quad*8);

    floatx4 zero = {0.f, 0.f, 0.f, 0.f};
    floatx4 accSA[4], accRA[4], accSB[4], accRB[4];
    for (int i = 0; i < 4; ++i) { accSA[i] = zero; accRA[i] = zero; accSB[i] = zero; accRB[i] = zero; }
    float lsumA = 0.f, lsumB = 0.f;

    unsigned* PW = (unsigned*)&Pbuf[wave][0];
    const int wb = l15*20 + quad*2;            // uint index within a 640-elem matrix
    const bf16* PR = &Pbuf[wave][l15*40 + quad*8];

    const bf16* kgp = kb + (size_t)l15 * QKVN + quad*8;    // row l15, d quad*8
    const bf16* vgp = vb + (size_t)l15 * NN + quad*8;

#pragma unroll 2
    for (int kt = 0; kt < 20; ++kt) {
        // K frags (A-operand): rows kt*32 + {l15, 16+l15}, d-halves 0/32
        short8 ak0lo = *(const short8*)(kgp);
        short8 ak0hi = *(const short8*)(kgp + 32);
        short8 ak1lo = *(const short8*)(kgp + 16*QKVN);
        short8 ak1hi = *(const short8*)(kgp + 16*QKVN + 32);
        kgp += 32 * QKVN;

        // V frags (B-operand): row d = dt*16+l15, tok = kt*32 + quad*8 + j
        short8 bv0 = *(const short8*)(vgp);
        short8 bv1 = *(const short8*)(vgp + 16*NN);
        short8 bv2 = *(const short8*)(vgp + 32*NN);
        short8 bv3 = *(const short8*)(vgp + 48*NN);
        vgp += 32;

        floatx4 sA0 = zero, sA1 = zero, sB0 = zero, sB1 = zero;
        sA0 = mfma16(ak0lo, aqA0, sA0);  sA0 = mfma16(ak0hi, aqA1, sA0);
        sA1 = mfma16(ak1lo, aqA0, sA1);  sA1 = mfma16(ak1hi, aqA1, sA1);
        sB0 = mfma16(ak0lo, aqB0, sB0);  sB0 = mfma16(ak0hi, aqB1, sB0);
        sB1 = mfma16(ak1lo, aqB0, sB1);  sB1 = mfma16(ak1hi, aqB1, sB1);

        // ---- group A ----
        {
            float ex0[4], ex1[4], rq0[4], rq1[4];
            for (int r = 0; r < 4; ++r) {
                ex0[r] = fexp2(sA0[r]);  ex1[r] = fexp2(sA1[r]);
                float m0 = fmaxf(sA0[r], 0.f), m1 = fmaxf(sA1[r], 0.f);
                rq0[r] = m0*m0;  rq1[r] = m1*m1;
                lsumA += ex0[r] + ex1[r];
            }
            *(uint2*)(PW + wb)           = make_uint2(pack_trunc(ex0[0],ex0[1]), pack_trunc(ex0[2],ex0[3]));
            *(uint2*)(PW + wb + 8)       = make_uint2(pack_trunc(ex1[0],ex1[1]), pack_trunc(ex1[2],ex1[3]));
            *(uint2*)(PW + 320 + wb)     = make_uint2(pack_trunc(rq0[0],rq0[1]), pack_trunc(rq0[2],rq0[3]));
            *(uint2*)(PW + 320 + wb + 8) = make_uint2(pack_trunc(rq1[0],rq1[1]), pack_trunc(rq1[2],rq1[3]));
            short8 paS = *(const short8*)(PR);
            short8 paR = *(const short8*)(PR + 640);
            accSA[0] = mfma16(paS, bv0, accSA[0]);  accRA[0] = mfma16(paR, bv0, accRA[0]);
            accSA[1] = mfma16(paS, bv1, accSA[1]);  accRA[1] = mfma16(paR, bv1, accRA[1]);
            accSA[2] = mfma16(paS, bv2, accSA[2]);  accRA[2] = mfma16(paR, bv2, accRA[2]);
            accSA[3] = mfma16(paS, bv3, accSA[3]);  accRA[3] = mfma16(paR, bv3, accRA[3]);
        }
        // ---- group B ----
        {
            float ex0[4], ex1[4], rq0[4], rq1[4];
            for (int r = 0; r < 4; ++r) {
                ex0[r] = fexp2(sB0[r]);  ex1[r] = fexp2(sB1[r]);
                float m0 = fmaxf(sB0[r], 0.f), m1 = fmaxf(sB1[r], 0.f);
                rq0[r] = m0*m0;  rq1[r] = m1*m1;
                lsumB += ex0[r] + ex1[r];
            }
            *(uint2*)(PW + 640 + wb)     = make_uint2(pack_trunc(ex0[0],ex0[1]), pack_trunc(ex0[2],ex0[3]));
            *(uint2*)(PW + 640 + wb + 8) = make_uint2(pack_trunc(ex1[0],ex1[1]), pack_trunc(ex1[2],ex1[3]));
            *(uint2*)(PW + 960 + wb)     = make_uint2(pack_trunc(rq0[0],rq0[1]), pack_trunc(rq0[2],rq0[3]));
            *(uint2*)(PW + 960 + wb + 8) = make_uint2(pack_trunc(rq1[0],rq1[1]), pack_trunc(rq1[2],rq1[3]));
            short8 paS = *(const short8*)(PR + 1280);
            short8 paR = *(const short8*)(PR + 1920);
            accSB[0] = mfma16(paS, bv0, accSB[0]);  accRB[0] = mfma16(paR, bv0, accRB[0]);
            accSB[1] = mfma16(paS, bv1, accSB[1]);  accRB[1] = mfma16(paR, bv1, accRB[1]);
            accSB[2] = mfma16(paS, bv2, accSB[2]);  accRB[2] = mfma16(paR, bv2, accRB[2]);
            accSB[3] = mfma16(paS, bv3, accSB[3]);  accRB[3] = mfma16(paR, bv3, accRB[3]);
        }
    }

    lsumA += __shfl_xor(lsumA, 16);  lsumA += __shfl_xor(lsumA, 32);
    lsumB += __shfl_xor(lsumB, 16);  lsumB += __shfl_xor(lsumB, 32);
    float invA[4], invB[4];
    for (int r = 0; r < 4; ++r) {
        invA[r] = 1.0f / __shfl(lsumA, quad*4 + r);
        invB[r] = 1.0f / __shfl(lsumB, quad*4 + r);
    }

    for (int dt = 0; dt < 4; ++dt) {
        for (int r = 0; r < 4; ++r) {
            int tokA = qrow0 + quad*4 + r;
            float vA = ws0 * accSA[dt][r] * invA[r] + ws1 * accRA[dt][r];
            ao[((size_t)(b * NN + tokA)) * DIM + h * HD + dt*16 + l15] = __float2bfloat16(vA);
            float vB = ws0 * accSB[dt][r] * invB[r] + ws1 * accRB[dt][r];
            ao[((size_t)(b * NN + tokA + 16)) * DIM + h * HD + dt*16 + l15] = __float2bfloat16(vB);
        }
    }
}

// ---------------- launch ----------------

extern "C" void kernel_launch(void* const* d_in, const int* in_sizes, int n_in,
                              void* d_out, int out_size, void* d_ws, size_t ws_size,
                              hipStream_t stream) {
    const float* x      = (const float*)d_in[0];
    const float* qkv_w  = (const float*)d_in[1];
    const float* qkv_b  = (const float*)d_in[2];
    const float* proj_w = (const float*)d_in[3];
    const float* proj_b = (const float*)d_in[4];
    const float* w2     = (const float*)d_in[5];
    float* out = (float*)d_out;

    bf16* xb   = (bf16*)d_ws;                       // 10240*768   (reused as ao later)
    bf16* qwT  = xb   + (size_t)MROWS * DIM;        // 2304*768
    bf16* pwT  = qwT  + (size_t)QKVN * DIM;         // 768*768
    bf16* qkvb = pwT  + (size_t)DIM * DIM;          // 10240*2304 (V cols unused)
    bf16* vT   = qkvb + (size_t)MROWS * QKVN;       // 192*64*640
    bf16* ao   = xb;                                 // alias: xb dead after qkv gemm

    cvt_x<<<(MROWS * DIM / 4 + 255) / 256, 256, 0, stream>>>(x, xb, MROWS * DIM / 4);
    tr_cvt<<<dim3(QKVN / 32, DIM / 32), dim3(32, 8), 0, stream>>>(qkv_w, qwT, DIM, QKVN);
    tr_cvt<<<dim3(DIM / 32, DIM / 32), dim3(32, 8), 0, stream>>>(proj_w, pwT, DIM, DIM);

    gemm_bt<0><<<dim3(QKVN / 128, MROWS / 128), 256, 0, stream>>>(
        xb, qwT, qkv_b, MROWS, QKVN, DIM, qkvb, vT, nullptr);

    attn_kernel<<<dim3(BH, NN / 128), 256, 0, stream>>>(qkvb, vT, w2, ao);

    gemm_bt<1><<<dim3(DIM / 128, MROWS / 128), 256, 0, stream>>>(
        ao, pwT, proj_b, MROWS, DIM, DIM, nullptr, nullptr, out);
}